// Round 6
// baseline (541.582 us; speedup 1.0000x reference)
//
#include <hip/hip_runtime.h>

#define NEGINF (-1e30f)

// ---------------- problem constants ----------------
// b=4, c=64, h=w=5, q=75, u=100, N_WAY=5, K_SHOT=5
// M_s = 125 (per way), M_u = 2500, M_q = 25, M_tot = 2625
// ---------------- workspace layout (float units) ----------------
constexpr size_t OF_UNL  = 0;                              // [4][2500][64]
constexpr size_t OF_SUP  = OF_UNL  + (size_t)4*2500*64;    // [4][5][125][64]
constexpr size_t OF_SUPT = OF_SUP  + (size_t)4*5*125*64;   // [4][5][64][128]
constexpr size_t OF_QT   = OF_SUPT + (size_t)4*5*64*128;   // [300][64][25]
constexpr size_t OF_ROWV = OF_QT   + (size_t)300*64*25;    // [4][5][4nc][2500] f
constexpr size_t OF_ROWI = OF_ROWV + (size_t)4*5*4*2500;   // [4][5][4nc][2500] i
constexpr size_t OF_CVI  = OF_ROWI + (size_t)4*5*4*2500;   // [4][5][125][20][2]
constexpr size_t OF_CMP  = OF_CVI  + (size_t)4*5*125*20*2; // [4][5][2500] i
constexpr size_t OF_CNT  = OF_CMP  + (size_t)4*5*2500;     // [20] i
constexpr size_t OF_UNEAR= OF_CNT  + 20;                   // [4][2500] i
constexpr size_t OF_SNEAR= OF_UNEAR+ 10000;                // [4][625]  i
constexpr size_t OF_BV   = OF_SNEAR+ 2500;                 // [300][5][25] f  per-way best val (== per-way max)
constexpr size_t OF_BP   = OF_BV   + 37500;                // [300][5][25] i  per-way best pack
constexpr size_t OF_AMX  = OF_BP   + 37500;                // [300][3200] u8  per-col argmax-over-mq

// ============================================================
// Kernel A: L2-normalize all three tensors into ws layouts.
// ============================================================
__global__ __launch_bounds__(256) void knorm(
    const float* __restrict__ sup, const float* __restrict__ qry,
    const float* __restrict__ unl,
    float* __restrict__ unl_n, float* __restrict__ sup_n,
    float* __restrict__ supT, float* __restrict__ qt)
{
    int gid = blockIdx.x * 256 + threadIdx.x;
    int loc = gid >> 4;
    int sub = gid & 15;
    if (loc >= 20000) return;

    const float* src;
    float* dst1; int dstr1;
    float* dst2 = nullptr;

    if (loc < 10000) {
        int b = loc / 2500, m = loc % 2500;
        int u = m / 25, hw = m % 25;
        src  = unl + ((size_t)(b*100 + u) * 64) * 25 + hw;
        dst1 = unl_n + (size_t)loc * 64; dstr1 = 1;
    } else if (loc < 12500) {
        int idx = loc - 10000;
        int b = idx / 625, r = idx % 625;
        int w = r / 125,  n = r % 125;
        int shot = n / 25, hw = n % 25;
        src  = sup + ((size_t)(b*25 + w*5 + shot) * 64) * 25 + hw;
        dst1 = sup_n + (size_t)idx * 64; dstr1 = 1;
        dst2 = supT + ((size_t)(b*5 + w) * 64) * 128 + n;
    } else {
        int idx = loc - 12500;
        int bq = idx / 25, mq = idx % 25;
        src  = qry + ((size_t)bq * 64) * 25 + mq;
        dst1 = qt + ((size_t)bq * 64) * 25 + mq; dstr1 = 25;
    }

    float v[4]; float ss = 0.f;
    int c0 = sub * 4;
#pragma unroll
    for (int j = 0; j < 4; ++j) { v[j] = src[(size_t)(c0 + j) * 25]; ss += v[j] * v[j]; }
#pragma unroll
    for (int msk = 1; msk < 16; msk <<= 1) ss += __shfl_xor(ss, msk);
    float sc = 1.f / fmaxf(sqrtf(ss), 1e-12f);
#pragma unroll
    for (int j = 0; j < 4; ++j) {
        float o = v[j] * sc;
        dst1[(size_t)(c0 + j) * dstr1] = o;
        if (dst2) dst2[(size_t)(c0 + j) * 128] = o;
    }
}

// ============================================================
// Kernel B: u2s pass. 1600 blocks x 128 (128 m x 32 n x 64 c each).
// ============================================================
__global__ __launch_bounds__(128) void kb(
    const float* __restrict__ unl_n, const float* __restrict__ supT,
    float* __restrict__ rowv, int* __restrict__ rowi, float* __restrict__ colvi)
{
    int bid = blockIdx.x;
    int nc = bid & 3;
    int mb = (bid >> 2) % 20;
    int bw = bid / 80;               // b*5+w
    int b  = bw / 5;
    int tid = threadIdx.x;
    int lane = tid & 63, wv = tid >> 6;

    __shared__ float uls[128 * 65];
    __shared__ float sv_[2][32];
    __shared__ int   si_[2][32];

    int m0 = mb * 128;
    for (int i = tid; i < 128 * 16; i += 128) {
        int row = i >> 4, c4 = (i & 15) * 4;
        int m = m0 + row;
        float4 x = make_float4(0.f, 0.f, 0.f, 0.f);
        if (m < 2500) x = *(const float4*)(unl_n + ((size_t)(b * 2500 + m)) * 64 + c4);
        uls[row * 65 + c4 + 0] = x.x;
        uls[row * 65 + c4 + 1] = x.y;
        uls[row * 65 + c4 + 2] = x.z;
        uls[row * 65 + c4 + 3] = x.w;
    }
    __syncthreads();

    int m = m0 + tid;
    int n0 = nc * 32;
    int nn = (125 - n0) < 32 ? (125 - n0) : 32;
    const float* sT = supT + ((size_t)bw * 64) * 128 + n0;
    const float* myrow = &uls[tid * 65];

    float acc[32];
#pragma unroll
    for (int j = 0; j < 32; ++j) acc[j] = 0.f;
    for (int c = 0; c < 64; ++c) {
        float uv = myrow[c];
        const float* srow = sT + c * 128;   // block-uniform -> scalar loads
#pragma unroll
        for (int j = 0; j < 32; ++j) acc[j] = fmaf(uv, srow[j], acc[j]);
    }

    // row-side running argmax (ascending n, strict > = first-tie)
    float rbv = NEGINF; int rbi = 0;
    for (int j = 0; j < nn; ++j)
        if (acc[j] > rbv) { rbv = acc[j]; rbi = n0 + j; }
    if (m < 2500) {
        rowv[((size_t)bw * 4 + nc) * 2500 + m] = rbv;
        rowi[((size_t)bw * 4 + nc) * 2500 + m] = rbi;
    }

    // col-side: wave max + ballot/ffs min-m tie-break
#pragma unroll
    for (int j = 0; j < 32; ++j) {
        float v = (m < 2500 && j < nn) ? acc[j] : NEGINF;
        float vm = v;
#pragma unroll
        for (int s2 = 1; s2 < 64; s2 <<= 1) vm = fmaxf(vm, __shfl_xor(vm, s2));
        unsigned long long msk = __ballot(v == vm);
        int first = __ffsll((unsigned long long)msk) - 1;   // lowest lane = smallest m
        if (lane == 0) { sv_[wv][j] = vm; si_[wv][j] = m0 + wv * 64 + first; }
    }
    __syncthreads();
    if (tid < nn) {
        float v = sv_[0][tid]; int vi = si_[0][tid];
        float v2 = sv_[1][tid]; int i2 = si_[1][tid];
        if (v2 > v || (v2 == v && i2 < vi)) { v = v2; vi = i2; }
        float* cv = colvi + ((((size_t)bw) * 125 + (n0 + tid)) * 20 + mb) * 2;
        cv[0] = v; ((int*)cv)[1] = vi;
    }
}

// ============================================================
// Kernel M: merge row partials -> unear, col partials -> snear.
// ============================================================
__global__ __launch_bounds__(256) void kmerge(
    const float* __restrict__ rowv, const int* __restrict__ rowi,
    const float* __restrict__ colvi,
    int* __restrict__ unear, int* __restrict__ snear)
{
    int it = blockIdx.x * 256 + threadIdx.x;
    if (it < 10000) {
        int b = it / 2500, m = it % 2500;
        float bv = NEGINF; int bi = 0;
#pragma unroll
        for (int w = 0; w < 5; ++w) {
#pragma unroll
            for (int nc = 0; nc < 4; ++nc) {
                size_t o = (((size_t)(b * 5 + w)) * 4 + nc) * 2500 + m;
                float v = rowv[o];
                if (v > bv) { bv = v; bi = w * 125 + rowi[o]; }
            }
        }
        unear[it] = bi;
    } else if (it < 12500) {
        int idx = it - 10000;
        const float* p = colvi + (size_t)idx * 40;
        float bv = NEGINF; int bi = 0x7fffffff;
        for (int mb2 = 0; mb2 < 20; ++mb2) {
            float v = p[mb2 * 2]; int vi = ((const int*)p)[mb2 * 2 + 1];
            if (v > bv || (v == bv && vi < bi)) { bv = v; bi = vi; }
        }
        snear[idx] = bi;
    }
}

// ============================================================
// Kernel P: mutual-NN mask + stable stream compaction. 20 blocks x 64.
// ============================================================
__global__ __launch_bounds__(64) void kcmp(
    const int* __restrict__ unear, const int* __restrict__ snear,
    int* __restrict__ cmp, int* __restrict__ cntg)
{
    int p = blockIdx.x;
    int b = p / 5, way = p % 5;
    int lane = threadIdx.x;
    int base = 0;
    for (int mc = 0; mc < 2500; mc += 64) {
        int m = mc + lane;
        bool ok = false;
        if (m < 2500) {
            int un = unear[b * 2500 + m];
            ok = (un / 125 == way) && (snear[b * 625 + un] == m);
        }
        unsigned long long msk = __ballot(ok ? 1 : 0);
        int pre = __popcll(msk & ((1ull << lane) - 1ull));
        if (ok) cmp[(size_t)p * 2500 + base + pre] = m;
        base += __popcll(msk);
    }
    if (lane == 0) cntg[p] = base;
}

// ============================================================
// Kernel C1: query similarity, one block (256 thr) per (bq, way).
// __launch_bounds__(256, 2): VGPR cap 256 (not the heuristic's 64) —
// keeps acc[25]+bestv/bestp[50]+R[8] in VGPRs, no AGPR shuffling
// (round-5 regression: 64-VGPR cap forced v_accvgpr traffic, ~2x VALU).
// ============================================================
__global__ __launch_bounds__(256, 2) void kc1(
    const float* __restrict__ qt, const float* __restrict__ sup_n,
    const float* __restrict__ unl_n, const int* __restrict__ cmp,
    const int* __restrict__ cntg,
    float* __restrict__ bvg, int* __restrict__ bpg,
    unsigned char* __restrict__ amaxg)
{
    int bid = blockIdx.x;
    int w = bid % 5, bq = bid / 5;
    int b = bq / 75;
    int tid = threadIdx.x;
    int lane = tid & 63, wv = tid >> 6;

    const float* qtb = qt + (size_t)bq * 64 * 25;

    int L = 0;
#pragma unroll
    for (int i = 0; i < 20; ++i) { int v = cntg[i]; L = L > v ? L : v; }
    int cntw = 0, wb = 0;
#pragma unroll
    for (int w2 = 0; w2 < 5; ++w2) {
        int c2 = cntg[b * 5 + w2];
        if (w2 < w) wb += 125 + c2;
        if (w2 == w) cntw = c2;
    }
    int cw = 125 + cntw;

    __shared__ float redf[4][25];
    __shared__ int   redi[4][25];

    float bestv[25]; int bestp[25];
#pragma unroll
    for (int i = 0; i < 25; ++i) { bestv[i] = NEGINF; bestp[i] = 0x7fffffff; }

    for (int n = tid; n < cw; n += 256) {
        const float* colp;
        if (n < 125) colp = sup_n + (((size_t)(b * 5 + w)) * 125 + n) * 64;
        else {
            int m = cmp[((size_t)(b * 5 + w)) * 2500 + (n - 125)];
            colp = unl_n + ((size_t)(b * 2500 + m)) * 64;
        }
        float acc[25];
#pragma unroll
        for (int i = 0; i < 25; ++i) acc[i] = 0.f;
        float4 R[8];
#pragma unroll
        for (int half = 0; half < 2; ++half) {
            int cbase = half * 32;
#pragma unroll
            for (int k = 0; k < 8; ++k) R[k] = *(const float4*)(colp + cbase + 4 * k);
#pragma unroll
            for (int k = 0; k < 8; ++k) {
                const float* qr = qtb + (cbase + 4 * k) * 25;   // block-uniform -> scalar
#pragma unroll
                for (int mq = 0; mq < 25; ++mq) {
                    acc[mq] = fmaf(R[k].x, qr[mq],      acc[mq]);
                    acc[mq] = fmaf(R[k].y, qr[25 + mq], acc[mq]);
                    acc[mq] = fmaf(R[k].z, qr[50 + mq], acc[mq]);
                    acc[mq] = fmaf(R[k].w, qr[75 + mq], acc[mq]);
                }
            }
        }
        float cmax = NEGINF; int cam = 0;
        int pos = wb + n;
        int pack = ((w * 2625 + n) << 12) | pos;
#pragma unroll
        for (int mq = 0; mq < 25; ++mq) {
            float s = (acc[mq] + 1.0f) * 0.5f;
            if (s > cmax) { cmax = s; cam = mq; }
            if (s > bestv[mq] || (s == bestv[mq] && pack < bestp[mq])) {
                bestv[mq] = s; bestp[mq] = pack;
            }
        }
        amaxg[(size_t)bq * 3200 + pos] = (unsigned char)cam;
    }

    // phantom (all-zero) columns: sim == 0.5, first at n = 125+cntw
    if (L > cntw) {
        int pack = ((w * 2625 + 125 + cntw) << 12) | 0xFFF;
#pragma unroll
        for (int mq = 0; mq < 25; ++mq) {
            if (0.5f > bestv[mq] || (0.5f == bestv[mq] && pack < bestp[mq])) {
                bestv[mq] = 0.5f; bestp[mq] = pack;
            }
        }
    }

    // slim wave reduction: value max, then pack min among ties
#pragma unroll
    for (int mq = 0; mq < 25; ++mq) {
        float v = bestv[mq];
#pragma unroll
        for (int s2 = 1; s2 < 64; s2 <<= 1) v = fmaxf(v, __shfl_xor(v, s2));
        int p = (bestv[mq] == v) ? bestp[mq] : 0x7fffffff;
#pragma unroll
        for (int s2 = 1; s2 < 64; s2 <<= 1) p = min(p, __shfl_xor(p, s2));
        bestv[mq] = v; bestp[mq] = p;
    }
    if (lane == 0) {
#pragma unroll
        for (int mq = 0; mq < 25; ++mq) { redf[wv][mq] = bestv[mq]; redi[wv][mq] = bestp[mq]; }
    }
    __syncthreads();
    if (tid < 25) {
        float v = fmaxf(fmaxf(redf[0][tid], redf[1][tid]),
                        fmaxf(redf[2][tid], redf[3][tid]));
        int p = 0x7fffffff;
#pragma unroll
        for (int k = 0; k < 4; ++k)
            if (redf[k][tid] == v) p = min(p, redi[k][tid]);
        size_t o = ((size_t)bq * 5 + w) * 25 + tid;
        bvg[o] = v; bpg[o] = p;
    }
}

// ============================================================
// Kernel CE: merge 5 way-partials per (bq,mq), mutual mask, row loss,
// atomicAdd into d_out. 300 blocks x 64. (d_out zeroed by memsetAsync.)
// ============================================================
__global__ __launch_bounds__(64) void kce(
    const float* __restrict__ bvg, const int* __restrict__ bpg,
    const unsigned char* __restrict__ amaxg, const int* __restrict__ qy,
    float* __restrict__ out)
{
    int bq = blockIdx.x;
    int tid = threadIdx.x;
    __shared__ float qmask[25];
    __shared__ float lg[5];
    if (tid < 25) {
        float v = NEGINF; int p = 0x7fffffff;
#pragma unroll
        for (int w = 0; w < 5; ++w) {
            size_t o = ((size_t)bq * 5 + w) * 25 + tid;
            float v2 = bvg[o]; int p2 = bpg[o];
            if (v2 > v || (v2 == v && p2 < p)) { v = v2; p = p2; }
        }
        int pos = p & 0xFFF;
        int g = (pos == 0xFFF) ? 0 : (int)amaxg[(size_t)bq * 3200 + pos];
        qmask[tid] = (g == tid) ? 1.0f : 0.0f;
    }
    __syncthreads();
    if (tid < 5) {
        float s = 0.f;
#pragma unroll
        for (int mq = 0; mq < 25; ++mq)
            s += bvg[((size_t)bq * 5 + tid) * 25 + mq] * qmask[mq];
        lg[tid] = s;
    }
    __syncthreads();
    if (tid == 0) {
        int y = qy[bq];
        float mx = lg[0];
#pragma unroll
        for (int w = 1; w < 5; ++w) mx = fmaxf(mx, lg[w]);
        float se = 0.f;
#pragma unroll
        for (int w = 0; w < 5; ++w) se += expf(lg[w] - mx);
        float loss = -(lg[y] - mx - logf(se));
        atomicAdd(out, loss * (1.0f / 300.0f));
    }
}

// ============================================================
extern "C" void kernel_launch(void* const* d_in, const int* in_sizes, int n_in,
                              void* d_out, int out_size, void* d_ws, size_t ws_size,
                              hipStream_t stream)
{
    const float* sup = (const float*)d_in[0];
    const float* qry = (const float*)d_in[2];
    const int*   qy  = (const int*)d_in[3];
    const float* unl = (const float*)d_in[4];

    float* ws    = (float*)d_ws;
    float* unl_n = ws + OF_UNL;
    float* sup_n = ws + OF_SUP;
    float* supT  = ws + OF_SUPT;
    float* qt    = ws + OF_QT;
    float* rowv  = ws + OF_ROWV;
    int*   rowi  = (int*)(ws + OF_ROWI);
    float* colvi = ws + OF_CVI;
    int*   cmp   = (int*)(ws + OF_CMP);
    int*   cntg  = (int*)(ws + OF_CNT);
    int*   unear = (int*)(ws + OF_UNEAR);
    int*   snear = (int*)(ws + OF_SNEAR);
    float* bvg   = ws + OF_BV;
    int*   bpg   = (int*)(ws + OF_BP);
    unsigned char* amaxg = (unsigned char*)(ws + OF_AMX);

    hipMemsetAsync(d_out, 0, sizeof(float), stream);

    hipLaunchKernelGGL(knorm, dim3(1250), dim3(256), 0, stream,
                       sup, qry, unl, unl_n, sup_n, supT, qt);
    hipLaunchKernelGGL(kb, dim3(1600), dim3(128), 0, stream,
                       unl_n, supT, rowv, rowi, colvi);
    hipLaunchKernelGGL(kmerge, dim3(49), dim3(256), 0, stream,
                       rowv, rowi, colvi, unear, snear);
    hipLaunchKernelGGL(kcmp, dim3(20), dim3(64), 0, stream,
                       unear, snear, cmp, cntg);
    hipLaunchKernelGGL(kc1, dim3(1500), dim3(256), 0, stream,
                       qt, sup_n, unl_n, cmp, cntg, bvg, bpg, amaxg);
    hipLaunchKernelGGL(kce, dim3(300), dim3(64), 0, stream,
                       bvg, bpg, amaxg, qy, (float*)d_out);
}

// Round 7
// 197.846 us; speedup vs baseline: 2.7374x; 2.7374x over previous
//
#include <hip/hip_runtime.h>

#define NEGINF (-1e30f)

// ---------------- problem constants ----------------
// b=4, c=64, h=w=5, q=75, u=100, N_WAY=5, K_SHOT=5
// M_s = 125 (per way), M_u = 2500, M_q = 25, M_tot = 2625
// ---------------- workspace layout (float units) ----------------
constexpr size_t OF_UNL  = 0;                              // [4][2500][64]
constexpr size_t OF_SUP  = OF_UNL  + (size_t)4*2500*64;    // [4][5][125][64]
constexpr size_t OF_SUPT = OF_SUP  + (size_t)4*5*125*64;   // [4][5][64][128]
constexpr size_t OF_QT   = OF_SUPT + (size_t)4*5*64*128;   // [300][64][25]
constexpr size_t OF_ROWV = OF_QT   + (size_t)300*64*25;    // [4][5][4nc][2500] f
constexpr size_t OF_ROWI = OF_ROWV + (size_t)4*5*4*2500;   // [4][5][4nc][2500] i
constexpr size_t OF_CVI  = OF_ROWI + (size_t)4*5*4*2500;   // [4][5][125][20][2]
constexpr size_t OF_CMP  = OF_CVI  + (size_t)4*5*125*20*2; // [4][5][2500] i
constexpr size_t OF_CNT  = OF_CMP  + (size_t)4*5*2500;     // [20] i
constexpr size_t OF_UNEAR= OF_CNT  + 20;                   // [4][2500] i
constexpr size_t OF_SNEAR= OF_UNEAR+ 10000;                // [4][625]  i
constexpr size_t OF_BV   = OF_SNEAR+ 2500;                 // [300][5][25] f  per-way best val (== per-way max)
constexpr size_t OF_BP   = OF_BV   + 37500;                // [300][5][25] i  per-way best pack
constexpr size_t OF_AMX  = OF_BP   + 37500;                // [300][3200] u8  per-col argmax-over-mq

// ============================================================
// Kernel A: L2-normalize all three tensors into ws layouts.
// ============================================================
__global__ __launch_bounds__(256) void knorm(
    const float* __restrict__ sup, const float* __restrict__ qry,
    const float* __restrict__ unl,
    float* __restrict__ unl_n, float* __restrict__ sup_n,
    float* __restrict__ supT, float* __restrict__ qt)
{
    int gid = blockIdx.x * 256 + threadIdx.x;
    int loc = gid >> 4;
    int sub = gid & 15;
    if (loc >= 20000) return;

    const float* src;
    float* dst1; int dstr1;
    float* dst2 = nullptr;

    if (loc < 10000) {
        int b = loc / 2500, m = loc % 2500;
        int u = m / 25, hw = m % 25;
        src  = unl + ((size_t)(b*100 + u) * 64) * 25 + hw;
        dst1 = unl_n + (size_t)loc * 64; dstr1 = 1;
    } else if (loc < 12500) {
        int idx = loc - 10000;
        int b = idx / 625, r = idx % 625;
        int w = r / 125,  n = r % 125;
        int shot = n / 25, hw = n % 25;
        src  = sup + ((size_t)(b*25 + w*5 + shot) * 64) * 25 + hw;
        dst1 = sup_n + (size_t)idx * 64; dstr1 = 1;
        dst2 = supT + ((size_t)(b*5 + w) * 64) * 128 + n;
    } else {
        int idx = loc - 12500;
        int bq = idx / 25, mq = idx % 25;
        src  = qry + ((size_t)bq * 64) * 25 + mq;
        dst1 = qt + ((size_t)bq * 64) * 25 + mq; dstr1 = 25;
    }

    float v[4]; float ss = 0.f;
    int c0 = sub * 4;
#pragma unroll
    for (int j = 0; j < 4; ++j) { v[j] = src[(size_t)(c0 + j) * 25]; ss += v[j] * v[j]; }
#pragma unroll
    for (int msk = 1; msk < 16; msk <<= 1) ss += __shfl_xor(ss, msk);
    float sc = 1.f / fmaxf(sqrtf(ss), 1e-12f);
#pragma unroll
    for (int j = 0; j < 4; ++j) {
        float o = v[j] * sc;
        dst1[(size_t)(c0 + j) * dstr1] = o;
        if (dst2) dst2[(size_t)(c0 + j) * 128] = o;
    }
}

// ============================================================
// Kernel B: u2s pass. 1600 blocks x 128 (128 m x 32 n x 64 c each).
// ============================================================
__global__ __launch_bounds__(128) void kb(
    const float* __restrict__ unl_n, const float* __restrict__ supT,
    float* __restrict__ rowv, int* __restrict__ rowi, float* __restrict__ colvi)
{
    int bid = blockIdx.x;
    int nc = bid & 3;
    int mb = (bid >> 2) % 20;
    int bw = bid / 80;               // b*5+w
    int b  = bw / 5;
    int tid = threadIdx.x;
    int lane = tid & 63, wv = tid >> 6;

    __shared__ float uls[128 * 65];
    __shared__ float sv_[2][32];
    __shared__ int   si_[2][32];

    int m0 = mb * 128;
    for (int i = tid; i < 128 * 16; i += 128) {
        int row = i >> 4, c4 = (i & 15) * 4;
        int m = m0 + row;
        float4 x = make_float4(0.f, 0.f, 0.f, 0.f);
        if (m < 2500) x = *(const float4*)(unl_n + ((size_t)(b * 2500 + m)) * 64 + c4);
        uls[row * 65 + c4 + 0] = x.x;
        uls[row * 65 + c4 + 1] = x.y;
        uls[row * 65 + c4 + 2] = x.z;
        uls[row * 65 + c4 + 3] = x.w;
    }
    __syncthreads();

    int m = m0 + tid;
    int n0 = nc * 32;
    int nn = (125 - n0) < 32 ? (125 - n0) : 32;
    const float* sT = supT + ((size_t)bw * 64) * 128 + n0;
    const float* myrow = &uls[tid * 65];

    float acc[32];
#pragma unroll
    for (int j = 0; j < 32; ++j) acc[j] = 0.f;
    for (int c = 0; c < 64; ++c) {
        float uv = myrow[c];
        const float* srow = sT + c * 128;   // block-uniform -> scalar loads
#pragma unroll
        for (int j = 0; j < 32; ++j) acc[j] = fmaf(uv, srow[j], acc[j]);
    }

    // row-side running argmax (ascending n, strict > = first-tie)
    float rbv = NEGINF; int rbi = 0;
    for (int j = 0; j < nn; ++j)
        if (acc[j] > rbv) { rbv = acc[j]; rbi = n0 + j; }
    if (m < 2500) {
        rowv[((size_t)bw * 4 + nc) * 2500 + m] = rbv;
        rowi[((size_t)bw * 4 + nc) * 2500 + m] = rbi;
    }

    // col-side: wave max + ballot/ffs min-m tie-break
#pragma unroll
    for (int j = 0; j < 32; ++j) {
        float v = (m < 2500 && j < nn) ? acc[j] : NEGINF;
        float vm = v;
#pragma unroll
        for (int s2 = 1; s2 < 64; s2 <<= 1) vm = fmaxf(vm, __shfl_xor(vm, s2));
        unsigned long long msk = __ballot(v == vm);
        int first = __ffsll((unsigned long long)msk) - 1;   // lowest lane = smallest m
        if (lane == 0) { sv_[wv][j] = vm; si_[wv][j] = m0 + wv * 64 + first; }
    }
    __syncthreads();
    if (tid < nn) {
        float v = sv_[0][tid]; int vi = si_[0][tid];
        float v2 = sv_[1][tid]; int i2 = si_[1][tid];
        if (v2 > v || (v2 == v && i2 < vi)) { v = v2; vi = i2; }
        float* cv = colvi + ((((size_t)bw) * 125 + (n0 + tid)) * 20 + mb) * 2;
        cv[0] = v; ((int*)cv)[1] = vi;
    }
}

// ============================================================
// Kernel M: merge row partials -> unear, col partials -> snear.
// ============================================================
__global__ __launch_bounds__(256) void kmerge(
    const float* __restrict__ rowv, const int* __restrict__ rowi,
    const float* __restrict__ colvi,
    int* __restrict__ unear, int* __restrict__ snear)
{
    int it = blockIdx.x * 256 + threadIdx.x;
    if (it < 10000) {
        int b = it / 2500, m = it % 2500;
        float bv = NEGINF; int bi = 0;
#pragma unroll
        for (int w = 0; w < 5; ++w) {
#pragma unroll
            for (int nc = 0; nc < 4; ++nc) {
                size_t o = (((size_t)(b * 5 + w)) * 4 + nc) * 2500 + m;
                float v = rowv[o];
                if (v > bv) { bv = v; bi = w * 125 + rowi[o]; }
            }
        }
        unear[it] = bi;
    } else if (it < 12500) {
        int idx = it - 10000;
        const float* p = colvi + (size_t)idx * 40;
        float bv = NEGINF; int bi = 0x7fffffff;
        for (int mb2 = 0; mb2 < 20; ++mb2) {
            float v = p[mb2 * 2]; int vi = ((const int*)p)[mb2 * 2 + 1];
            if (v > bv || (v == bv && vi < bi)) { bv = v; bi = vi; }
        }
        snear[idx] = bi;
    }
}

// ============================================================
// Kernel P: mutual-NN mask + stable stream compaction. 20 blocks x 64.
// ============================================================
__global__ __launch_bounds__(64) void kcmp(
    const int* __restrict__ unear, const int* __restrict__ snear,
    int* __restrict__ cmp, int* __restrict__ cntg)
{
    int p = blockIdx.x;
    int b = p / 5, way = p % 5;
    int lane = threadIdx.x;
    int base = 0;
    for (int mc = 0; mc < 2500; mc += 64) {
        int m = mc + lane;
        bool ok = false;
        if (m < 2500) {
            int un = unear[b * 2500 + m];
            ok = (un / 125 == way) && (snear[b * 625 + un] == m);
        }
        unsigned long long msk = __ballot(ok ? 1 : 0);
        int pre = __popcll(msk & ((1ull << lane) - 1ull));
        if (ok) cmp[(size_t)p * 2500 + base + pre] = m;
        base += __popcll(msk);
    }
    if (lane == 0) cntg[p] = base;
}

// ============================================================
// Kernel C1: query similarity, one block (256 thr) per (bq, way).
// Register-pressure restructure (round-6 post-mortem): per-thread
// live state in the main loop is ONLY acc[25] (~50 VGPR total) —
// per-mq best tracking moved to a per-chunk LDS transpose + reduce
// phase where each thread owns ONE mq (2 regs). No best arrays in
// the hot loop -> no spill (r6: 28 MB scratch writes) and no AGPR
// shuffling (r5). LDS sim buffer stride 257 = conflict-free both ways.
// Exact tie-breaks preserved: reduce scans ascending pos, strict >.
// ============================================================
__global__ __launch_bounds__(256) void kc1(
    const float* __restrict__ qt, const float* __restrict__ sup_n,
    const float* __restrict__ unl_n, const int* __restrict__ cmp,
    const int* __restrict__ cntg,
    float* __restrict__ bvg, int* __restrict__ bpg,
    unsigned char* __restrict__ amaxg)
{
    int bid = blockIdx.x;
    int w = bid % 5, bq = bid / 5;
    int b = bq / 75;
    int tid = threadIdx.x;

    const float* qtb = qt + (size_t)bq * 64 * 25;

    int L = 0;
#pragma unroll
    for (int i = 0; i < 20; ++i) { int v = cntg[i]; L = L > v ? L : v; }
    int cntw = 0, wb = 0;
#pragma unroll
    for (int w2 = 0; w2 < 5; ++w2) {
        int c2 = cntg[b * 5 + w2];
        if (w2 < w) wb += 125 + c2;
        if (w2 == w) cntw = c2;
    }
    int cw = 125 + cntw;

    __shared__ float simb[25 * 257];   // [mq][col-in-chunk], stride 257
    __shared__ float redv[8][25];
    __shared__ int   redp[8][25];

    // per-thread reduce-phase state: one mq, one col-group
    int rg = tid / 25, rq = tid % 25;  // valid for tid < 200 (8 groups x 32 cols)
    float bv1 = NEGINF; int bp1 = 0x7fffffff;

    for (int c0 = 0; c0 < cw; c0 += 256) {
        int n = c0 + tid;
        if (n < cw) {
            const float* colp;
            if (n < 125) colp = sup_n + (((size_t)(b * 5 + w)) * 125 + n) * 64;
            else {
                int m = cmp[((size_t)(b * 5 + w)) * 2500 + (n - 125)];
                colp = unl_n + ((size_t)(b * 2500 + m)) * 64;
            }
            float acc[25];
#pragma unroll
            for (int i = 0; i < 25; ++i) acc[i] = 0.f;
            for (int c = 0; c < 64; c += 4) {
                float4 cv = *(const float4*)(colp + c);
                const float* qr = qtb + c * 25;   // block-uniform -> scalar loads
#pragma unroll
                for (int mq = 0; mq < 25; ++mq) {
                    acc[mq] = fmaf(cv.x, qr[mq],      acc[mq]);
                    acc[mq] = fmaf(cv.y, qr[25 + mq], acc[mq]);
                    acc[mq] = fmaf(cv.z, qr[50 + mq], acc[mq]);
                    acc[mq] = fmaf(cv.w, qr[75 + mq], acc[mq]);
                }
            }
            float cmax = NEGINF; int cam = 0;
#pragma unroll
            for (int mq = 0; mq < 25; ++mq) {
                float s = (acc[mq] + 1.0f) * 0.5f;
                if (s > cmax) { cmax = s; cam = mq; }
                simb[mq * 257 + tid] = s;     // consecutive lanes -> consecutive banks
            }
            amaxg[(size_t)bq * 3200 + (wb + n)] = (unsigned char)cam;
        }
        __syncthreads();
        // transposed reduce: thread (rg, rq) scans 32 cols of its mq,
        // ascending pos, strict > keeps first (exact tie semantics)
        if (tid < 200) {
            int base = rg * 32;
            for (int i = 0; i < 32; ++i) {
                int n2 = c0 + base + i;
                if (n2 < cw) {
                    float s = simb[rq * 257 + base + i];
                    if (s > bv1) { bv1 = s; bp1 = ((w * 2625 + n2) << 12) | (wb + n2); }
                }
            }
        }
        __syncthreads();
    }

    if (tid < 200) { redv[rg][rq] = bv1; redp[rg][rq] = bp1; }
    __syncthreads();
    if (tid < 25) {
        float v = redv[0][tid]; int p = redp[0][tid];
#pragma unroll
        for (int g = 1; g < 8; ++g)
            if (redv[g][tid] > v) { v = redv[g][tid]; p = redp[g][tid]; }  // strict > keeps earlier pos
        // phantom (all-zero) columns: sim == 0.5, first at n = 125+cntw
        if (L > cntw) {
            int pp = ((w * 2625 + 125 + cntw) << 12) | 0xFFF;
            if (0.5f > v || (0.5f == v && pp < p)) { v = 0.5f; p = pp; }
        }
        size_t o = ((size_t)bq * 5 + w) * 25 + tid;
        bvg[o] = v; bpg[o] = p;
    }
}

// ============================================================
// Kernel CE: merge 5 way-partials per (bq,mq), mutual mask, row loss,
// atomicAdd into d_out. 300 blocks x 64. (d_out zeroed by memsetAsync.)
// ============================================================
__global__ __launch_bounds__(64) void kce(
    const float* __restrict__ bvg, const int* __restrict__ bpg,
    const unsigned char* __restrict__ amaxg, const int* __restrict__ qy,
    float* __restrict__ out)
{
    int bq = blockIdx.x;
    int tid = threadIdx.x;
    __shared__ float qmask[25];
    __shared__ float lg[5];
    if (tid < 25) {
        float v = NEGINF; int p = 0x7fffffff;
#pragma unroll
        for (int w = 0; w < 5; ++w) {
            size_t o = ((size_t)bq * 5 + w) * 25 + tid;
            float v2 = bvg[o]; int p2 = bpg[o];
            if (v2 > v || (v2 == v && p2 < p)) { v = v2; p = p2; }
        }
        int pos = p & 0xFFF;
        int g = (pos == 0xFFF) ? 0 : (int)amaxg[(size_t)bq * 3200 + pos];
        qmask[tid] = (g == tid) ? 1.0f : 0.0f;
    }
    __syncthreads();
    if (tid < 5) {
        float s = 0.f;
#pragma unroll
        for (int mq = 0; mq < 25; ++mq)
            s += bvg[((size_t)bq * 5 + tid) * 25 + mq] * qmask[mq];
        lg[tid] = s;
    }
    __syncthreads();
    if (tid == 0) {
        int y = qy[bq];
        float mx = lg[0];
#pragma unroll
        for (int w = 1; w < 5; ++w) mx = fmaxf(mx, lg[w]);
        float se = 0.f;
#pragma unroll
        for (int w = 0; w < 5; ++w) se += expf(lg[w] - mx);
        float loss = -(lg[y] - mx - logf(se));
        atomicAdd(out, loss * (1.0f / 300.0f));
    }
}

// ============================================================
extern "C" void kernel_launch(void* const* d_in, const int* in_sizes, int n_in,
                              void* d_out, int out_size, void* d_ws, size_t ws_size,
                              hipStream_t stream)
{
    const float* sup = (const float*)d_in[0];
    const float* qry = (const float*)d_in[2];
    const int*   qy  = (const int*)d_in[3];
    const float* unl = (const float*)d_in[4];

    float* ws    = (float*)d_ws;
    float* unl_n = ws + OF_UNL;
    float* sup_n = ws + OF_SUP;
    float* supT  = ws + OF_SUPT;
    float* qt    = ws + OF_QT;
    float* rowv  = ws + OF_ROWV;
    int*   rowi  = (int*)(ws + OF_ROWI);
    float* colvi = ws + OF_CVI;
    int*   cmp   = (int*)(ws + OF_CMP);
    int*   cntg  = (int*)(ws + OF_CNT);
    int*   unear = (int*)(ws + OF_UNEAR);
    int*   snear = (int*)(ws + OF_SNEAR);
    float* bvg   = ws + OF_BV;
    int*   bpg   = (int*)(ws + OF_BP);
    unsigned char* amaxg = (unsigned char*)(ws + OF_AMX);

    hipMemsetAsync(d_out, 0, sizeof(float), stream);

    hipLaunchKernelGGL(knorm, dim3(1250), dim3(256), 0, stream,
                       sup, qry, unl, unl_n, sup_n, supT, qt);
    hipLaunchKernelGGL(kb, dim3(1600), dim3(128), 0, stream,
                       unl_n, supT, rowv, rowi, colvi);
    hipLaunchKernelGGL(kmerge, dim3(49), dim3(256), 0, stream,
                       rowv, rowi, colvi, unear, snear);
    hipLaunchKernelGGL(kcmp, dim3(20), dim3(64), 0, stream,
                       unear, snear, cmp, cntg);
    hipLaunchKernelGGL(kc1, dim3(1500), dim3(256), 0, stream,
                       qt, sup_n, unl_n, cmp, cntg, bvg, bpg, amaxg);
    hipLaunchKernelGGL(kce, dim3(300), dim3(64), 0, stream,
                       bvg, bpg, amaxg, qy, (float*)d_out);
}

// Round 8
// 181.443 us; speedup vs baseline: 2.9849x; 1.0904x over previous
//
#include <hip/hip_runtime.h>

#define NEGINF (-1e30f)

// ---------------- problem constants ----------------
// b=4, c=64, h=w=5, q=75, u=100, N_WAY=5, K_SHOT=5
// M_s = 125 (per way), M_u = 2500, M_q = 25, M_tot = 2625
// ---------------- workspace layout (float units) ----------------
constexpr size_t OF_UNL  = 0;                              // [4][2500][64]
constexpr size_t OF_SUP  = OF_UNL  + (size_t)4*2500*64;    // [4][5][125][64]
constexpr size_t OF_SUPT = OF_SUP  + (size_t)4*5*125*64;   // [4][5][64][128]
constexpr size_t OF_QT   = OF_SUPT + (size_t)4*5*64*128;   // [300][64][25]
constexpr size_t OF_ROWV = OF_QT   + (size_t)300*64*25;    // [4][5][8ck][2500] f
constexpr size_t OF_ROWI = OF_ROWV + (size_t)4*5*8*2500;   // [4][5][8ck][2500] i
constexpr size_t OF_CVI  = OF_ROWI + (size_t)4*5*8*2500;   // [4][5][125][20][2]
constexpr size_t OF_CMP  = OF_CVI  + (size_t)4*5*125*20*2; // [4][5][2500] i
constexpr size_t OF_CNT  = OF_CMP  + (size_t)4*5*2500;     // [20] i
constexpr size_t OF_UNEAR= OF_CNT  + 20;                   // [4][2500] i
constexpr size_t OF_SNEAR= OF_UNEAR+ 10000;                // [4][625]  i
constexpr size_t OF_BV   = OF_SNEAR+ 2500;                 // [300][5][25] f
constexpr size_t OF_BP   = OF_BV   + 37500;                // [300][5][25] i
constexpr size_t OF_AMX  = OF_BP   + 37500;                // [300][3200] u8

// ============================================================
// Kernel A: L2-normalize all three tensors into ws layouts.
// ============================================================
__global__ __launch_bounds__(256) void knorm(
    const float* __restrict__ sup, const float* __restrict__ qry,
    const float* __restrict__ unl,
    float* __restrict__ unl_n, float* __restrict__ sup_n,
    float* __restrict__ supT, float* __restrict__ qt)
{
    int gid = blockIdx.x * 256 + threadIdx.x;
    int loc = gid >> 4;
    int sub = gid & 15;
    if (loc >= 20000) return;

    const float* src;
    float* dst1; int dstr1;
    float* dst2 = nullptr;

    if (loc < 10000) {
        int b = loc / 2500, m = loc % 2500;
        int u = m / 25, hw = m % 25;
        src  = unl + ((size_t)(b*100 + u) * 64) * 25 + hw;
        dst1 = unl_n + (size_t)loc * 64; dstr1 = 1;
    } else if (loc < 12500) {
        int idx = loc - 10000;
        int b = idx / 625, r = idx % 625;
        int w = r / 125,  n = r % 125;
        int shot = n / 25, hw = n % 25;
        src  = sup + ((size_t)(b*25 + w*5 + shot) * 64) * 25 + hw;
        dst1 = sup_n + (size_t)idx * 64; dstr1 = 1;
        dst2 = supT + ((size_t)(b*5 + w) * 64) * 128 + n;
    } else {
        int idx = loc - 12500;
        int bq = idx / 25, mq = idx % 25;
        src  = qry + ((size_t)bq * 64) * 25 + mq;
        dst1 = qt + ((size_t)bq * 64) * 25 + mq; dstr1 = 25;
    }

    float v[4]; float ss = 0.f;
    int c0 = sub * 4;
#pragma unroll
    for (int j = 0; j < 4; ++j) { v[j] = src[(size_t)(c0 + j) * 25]; ss += v[j] * v[j]; }
#pragma unroll
    for (int msk = 1; msk < 16; msk <<= 1) ss += __shfl_xor(ss, msk);
    float sc = 1.f / fmaxf(sqrtf(ss), 1e-12f);
#pragma unroll
    for (int j = 0; j < 4; ++j) {
        float o = v[j] * sc;
        dst1[(size_t)(c0 + j) * dstr1] = o;
        if (dst2) dst2[(size_t)(c0 + j) * 128] = o;
    }
}

// ============================================================
// Kernel B: u2s pass. 1600 blocks x 256 threads.
// Tile: 128 m x 32 n x 64 c; thread = (m, n-half of 16).
// Round-7 fix: sup tile staged in LDS, read via uniform-address
// ds_read_b128 (HW broadcast) — the "compiler will scalar-promote
// block-uniform global loads" assumption was wrong (2048 same-addr
// VMEM loads/wave made kb VMEM-latency-bound at VALUBusy 19%).
// sls stride 36: b128-aligned reads; staging writes ~8-way conflict
// on 2 instr/thread only. uls stride 65: (m+c)%32 2-way = free.
// ============================================================
__global__ __launch_bounds__(256) void kb(
    const float* __restrict__ unl_n, const float* __restrict__ supT,
    float* __restrict__ rowv, int* __restrict__ rowi, float* __restrict__ colvi)
{
    int bid = blockIdx.x;
    int nc = bid & 3;
    int mb = (bid >> 2) % 20;
    int bw = bid / 80;               // b*5+w
    int b  = bw / 5;
    int tid = threadIdx.x;
    int lane = tid & 63, wv = tid >> 6;

    __shared__ float uls[128 * 65];
    __shared__ float sls[64 * 36];
    __shared__ float sv_[4][32];
    __shared__ int   si_[4][32];

    int m0 = mb * 128;
    int n0 = nc * 32;

    // stage 128 unl rows (zero-fill past 2500): 8 float4 per thread
    for (int i = tid; i < 128 * 16; i += 256) {
        int row = i >> 4, c4 = (i & 15) * 4;
        int m = m0 + row;
        float4 x = make_float4(0.f, 0.f, 0.f, 0.f);
        if (m < 2500) x = *(const float4*)(unl_n + ((size_t)(b * 2500 + m)) * 64 + c4);
        uls[row * 65 + c4 + 0] = x.x;
        uls[row * 65 + c4 + 1] = x.y;
        uls[row * 65 + c4 + 2] = x.z;
        uls[row * 65 + c4 + 3] = x.w;
    }
    // stage sup tile [64c][32n] (stride 36): thread (c=tid>>2, q=tid&3)
    {
        int c = tid >> 2, q = tid & 3;
        const float* sp = supT + ((size_t)bw * 64 + c) * 128 + n0 + q * 8;
        float4 a = *(const float4*)sp;
        float4 d4 = *(const float4*)(sp + 4);
        float* d = &sls[c * 36 + q * 8];
        d[0] = a.x; d[1] = a.y; d[2] = a.z; d[3] = a.w;
        d[4] = d4.x; d[5] = d4.y; d[6] = d4.z; d[7] = d4.w;
    }
    __syncthreads();

    int ml = tid & 127;              // local m
    int m  = m0 + ml;
    int nh = tid >> 7;               // n-half: 0 or 1
    int nbase = nh * 16;
    int nn_total = (125 - n0) < 32 ? (125 - n0) : 32;   // 32,32,32,29
    const float* myrow = &uls[ml * 65];

    float acc[16];
#pragma unroll
    for (int j = 0; j < 16; ++j) acc[j] = 0.f;

    for (int c = 0; c < 64; ++c) {
        float uv = myrow[c];
        const float4* sr = (const float4*)&sls[c * 36 + nbase];  // uniform -> broadcast
        float4 s0 = sr[0], s1 = sr[1], s2 = sr[2], s3 = sr[3];
        acc[0]  = fmaf(uv, s0.x, acc[0]);  acc[1]  = fmaf(uv, s0.y, acc[1]);
        acc[2]  = fmaf(uv, s0.z, acc[2]);  acc[3]  = fmaf(uv, s0.w, acc[3]);
        acc[4]  = fmaf(uv, s1.x, acc[4]);  acc[5]  = fmaf(uv, s1.y, acc[5]);
        acc[6]  = fmaf(uv, s1.z, acc[6]);  acc[7]  = fmaf(uv, s1.w, acc[7]);
        acc[8]  = fmaf(uv, s2.x, acc[8]);  acc[9]  = fmaf(uv, s2.y, acc[9]);
        acc[10] = fmaf(uv, s2.z, acc[10]); acc[11] = fmaf(uv, s2.w, acc[11]);
        acc[12] = fmaf(uv, s3.x, acc[12]); acc[13] = fmaf(uv, s3.y, acc[13]);
        acc[14] = fmaf(uv, s3.z, acc[14]); acc[15] = fmaf(uv, s3.w, acc[15]);
    }

    // row-side running argmax over this thread's 16 n's (ascending, strict >)
    int nnloc = nn_total - nbase;
    nnloc = nnloc < 0 ? 0 : (nnloc > 16 ? 16 : nnloc);
    float rbv = NEGINF; int rbi = 0;
    for (int j = 0; j < nnloc; ++j)
        if (acc[j] > rbv) { rbv = acc[j]; rbi = n0 + nbase + j; }
    if (m < 2500) {
        int ck = nc * 2 + nh;        // chunk 0..7, ascending global n
        rowv[((size_t)bw * 8 + ck) * 2500 + m] = rbv;
        rowi[((size_t)bw * 8 + ck) * 2500 + m] = rbi;
    }

    // col-side: wave max + ballot/ffs min-m tie-break
    // wave wv holds m = m0 + (wv&1)*64 + lane, n-half nh = wv>>1
#pragma unroll
    for (int j = 0; j < 16; ++j) {
        float v = (m < 2500 && (nbase + j) < nn_total) ? acc[j] : NEGINF;
        float vm = v;
#pragma unroll
        for (int s2 = 1; s2 < 64; s2 <<= 1) vm = fmaxf(vm, __shfl_xor(vm, s2));
        unsigned long long msk = __ballot(v == vm);
        int first = __ffsll((unsigned long long)msk) - 1;
        if (lane == 0) { sv_[wv][nbase + j] = vm; si_[wv][nbase + j] = m0 + (wv & 1) * 64 + first; }
    }
    __syncthreads();
    if (tid < nn_total) {
        int w0 = (tid < 16) ? 0 : 2;
        float v = sv_[w0][tid];     int vi = si_[w0][tid];
        float v2 = sv_[w0 + 1][tid]; int i2 = si_[w0 + 1][tid];
        if (v2 > v || (v2 == v && i2 < vi)) { v = v2; vi = i2; }
        float* cv = colvi + ((((size_t)bw) * 125 + (n0 + tid)) * 20 + mb) * 2;
        cv[0] = v; ((int*)cv)[1] = vi;
    }
}

// ============================================================
// Kernel M: merge row partials -> unear (5w x 8ck ascending global n),
// col partials -> snear. 49 blocks x 256.
// ============================================================
__global__ __launch_bounds__(256) void kmerge(
    const float* __restrict__ rowv, const int* __restrict__ rowi,
    const float* __restrict__ colvi,
    int* __restrict__ unear, int* __restrict__ snear)
{
    int it = blockIdx.x * 256 + threadIdx.x;
    if (it < 10000) {
        int b = it / 2500, m = it % 2500;
        float bv = NEGINF; int bi = 0;
#pragma unroll
        for (int w = 0; w < 5; ++w) {
#pragma unroll
            for (int ck = 0; ck < 8; ++ck) {
                size_t o = (((size_t)(b * 5 + w)) * 8 + ck) * 2500 + m;
                float v = rowv[o];
                if (v > bv) { bv = v; bi = w * 125 + rowi[o]; }
            }
        }
        unear[it] = bi;
    } else if (it < 12500) {
        int idx = it - 10000;
        const float* p = colvi + (size_t)idx * 40;
        float bv = NEGINF; int bi = 0x7fffffff;
        for (int mb2 = 0; mb2 < 20; ++mb2) {
            float v = p[mb2 * 2]; int vi = ((const int*)p)[mb2 * 2 + 1];
            if (v > bv || (v == bv && vi < bi)) { bv = v; bi = vi; }
        }
        snear[idx] = bi;
    }
}

// ============================================================
// Kernel P: mutual-NN mask + stable stream compaction.
// Round-7 fix: parallel flag phase (no 40-deep dependent-load chain),
// serial 40-word prefix in LDS, parallel scatter. 20 blocks x 256.
// ============================================================
__global__ __launch_bounds__(256) void kcmp(
    const int* __restrict__ unear, const int* __restrict__ snear,
    int* __restrict__ cmp, int* __restrict__ cntg)
{
    int p = blockIdx.x;
    int b = p / 5, way = p % 5;
    int tid = threadIdx.x, lane = tid & 63, wv = tid >> 6;
    __shared__ unsigned long long masks[40];
    __shared__ int base[40];

    for (int ch = wv; ch < 40; ch += 4) {
        int m = ch * 64 + lane;
        bool ok = false;
        if (m < 2500) {
            int un = unear[b * 2500 + m];
            ok = (un / 125 == way) && (snear[b * 625 + un] == m);
        }
        unsigned long long msk = __ballot(ok ? 1 : 0);
        if (lane == 0) masks[ch] = msk;
    }
    __syncthreads();
    if (tid == 0) {
        int s = 0;
        for (int ch = 0; ch < 40; ++ch) { base[ch] = s; s += __popcll(masks[ch]); }
        cntg[p] = s;
    }
    __syncthreads();
    for (int ch = wv; ch < 40; ch += 4) {
        unsigned long long msk = masks[ch];
        if ((msk >> lane) & 1ull) {
            int pre = __popcll(msk & ((1ull << lane) - 1ull));
            cmp[(size_t)p * 2500 + base[ch] + pre] = ch * 64 + lane;
        }
    }
}

// ============================================================
// Kernel C1: query similarity, one block (256 thr) per (bq, way).
// (unchanged from round 7 — LDS-transpose reduce, ~50 VGPR hot loop)
// ============================================================
__global__ __launch_bounds__(256) void kc1(
    const float* __restrict__ qt, const float* __restrict__ sup_n,
    const float* __restrict__ unl_n, const int* __restrict__ cmp,
    const int* __restrict__ cntg,
    float* __restrict__ bvg, int* __restrict__ bpg,
    unsigned char* __restrict__ amaxg)
{
    int bid = blockIdx.x;
    int w = bid % 5, bq = bid / 5;
    int b = bq / 75;
    int tid = threadIdx.x;

    const float* qtb = qt + (size_t)bq * 64 * 25;

    int L = 0;
#pragma unroll
    for (int i = 0; i < 20; ++i) { int v = cntg[i]; L = L > v ? L : v; }
    int cntw = 0, wb = 0;
#pragma unroll
    for (int w2 = 0; w2 < 5; ++w2) {
        int c2 = cntg[b * 5 + w2];
        if (w2 < w) wb += 125 + c2;
        if (w2 == w) cntw = c2;
    }
    int cw = 125 + cntw;

    __shared__ float simb[25 * 257];
    __shared__ float redv[8][25];
    __shared__ int   redp[8][25];

    int rg = tid / 25, rq = tid % 25;
    float bv1 = NEGINF; int bp1 = 0x7fffffff;

    for (int c0 = 0; c0 < cw; c0 += 256) {
        int n = c0 + tid;
        if (n < cw) {
            const float* colp;
            if (n < 125) colp = sup_n + (((size_t)(b * 5 + w)) * 125 + n) * 64;
            else {
                int m = cmp[((size_t)(b * 5 + w)) * 2500 + (n - 125)];
                colp = unl_n + ((size_t)(b * 2500 + m)) * 64;
            }
            float acc[25];
#pragma unroll
            for (int i = 0; i < 25; ++i) acc[i] = 0.f;
            for (int c = 0; c < 64; c += 4) {
                float4 cv = *(const float4*)(colp + c);
                const float* qr = qtb + c * 25;
#pragma unroll
                for (int mq = 0; mq < 25; ++mq) {
                    acc[mq] = fmaf(cv.x, qr[mq],      acc[mq]);
                    acc[mq] = fmaf(cv.y, qr[25 + mq], acc[mq]);
                    acc[mq] = fmaf(cv.z, qr[50 + mq], acc[mq]);
                    acc[mq] = fmaf(cv.w, qr[75 + mq], acc[mq]);
                }
            }
            float cmax = NEGINF; int cam = 0;
#pragma unroll
            for (int mq = 0; mq < 25; ++mq) {
                float s = (acc[mq] + 1.0f) * 0.5f;
                if (s > cmax) { cmax = s; cam = mq; }
                simb[mq * 257 + tid] = s;
            }
            amaxg[(size_t)bq * 3200 + (wb + n)] = (unsigned char)cam;
        }
        __syncthreads();
        if (tid < 200) {
            int base = rg * 32;
            for (int i = 0; i < 32; ++i) {
                int n2 = c0 + base + i;
                if (n2 < cw) {
                    float s = simb[rq * 257 + base + i];
                    if (s > bv1) { bv1 = s; bp1 = ((w * 2625 + n2) << 12) | (wb + n2); }
                }
            }
        }
        __syncthreads();
    }

    if (tid < 200) { redv[rg][rq] = bv1; redp[rg][rq] = bp1; }
    __syncthreads();
    if (tid < 25) {
        float v = redv[0][tid]; int p = redp[0][tid];
#pragma unroll
        for (int g = 1; g < 8; ++g)
            if (redv[g][tid] > v) { v = redv[g][tid]; p = redp[g][tid]; }
        if (L > cntw) {
            int pp = ((w * 2625 + 125 + cntw) << 12) | 0xFFF;
            if (0.5f > v || (0.5f == v && pp < p)) { v = 0.5f; p = pp; }
        }
        size_t o = ((size_t)bq * 5 + w) * 25 + tid;
        bvg[o] = v; bpg[o] = p;
    }
}

// ============================================================
// Kernel CE: merge 5 way-partials per (bq,mq), mutual mask, row loss,
// atomicAdd into d_out. 300 blocks x 64.
// ============================================================
__global__ __launch_bounds__(64) void kce(
    const float* __restrict__ bvg, const int* __restrict__ bpg,
    const unsigned char* __restrict__ amaxg, const int* __restrict__ qy,
    float* __restrict__ out)
{
    int bq = blockIdx.x;
    int tid = threadIdx.x;
    __shared__ float qmask[25];
    __shared__ float lg[5];
    if (tid < 25) {
        float v = NEGINF; int p = 0x7fffffff;
#pragma unroll
        for (int w = 0; w < 5; ++w) {
            size_t o = ((size_t)bq * 5 + w) * 25 + tid;
            float v2 = bvg[o]; int p2 = bpg[o];
            if (v2 > v || (v2 == v && p2 < p)) { v = v2; p = p2; }
        }
        int pos = p & 0xFFF;
        int g = (pos == 0xFFF) ? 0 : (int)amaxg[(size_t)bq * 3200 + pos];
        qmask[tid] = (g == tid) ? 1.0f : 0.0f;
    }
    __syncthreads();
    if (tid < 5) {
        float s = 0.f;
#pragma unroll
        for (int mq = 0; mq < 25; ++mq)
            s += bvg[((size_t)bq * 5 + tid) * 25 + mq] * qmask[mq];
        lg[tid] = s;
    }
    __syncthreads();
    if (tid == 0) {
        int y = qy[bq];
        float mx = lg[0];
#pragma unroll
        for (int w = 1; w < 5; ++w) mx = fmaxf(mx, lg[w]);
        float se = 0.f;
#pragma unroll
        for (int w = 0; w < 5; ++w) se += expf(lg[w] - mx);
        float loss = -(lg[y] - mx - logf(se));
        atomicAdd(out, loss * (1.0f / 300.0f));
    }
}

// ============================================================
extern "C" void kernel_launch(void* const* d_in, const int* in_sizes, int n_in,
                              void* d_out, int out_size, void* d_ws, size_t ws_size,
                              hipStream_t stream)
{
    const float* sup = (const float*)d_in[0];
    const float* qry = (const float*)d_in[2];
    const int*   qy  = (const int*)d_in[3];
    const float* unl = (const float*)d_in[4];

    float* ws    = (float*)d_ws;
    float* unl_n = ws + OF_UNL;
    float* sup_n = ws + OF_SUP;
    float* supT  = ws + OF_SUPT;
    float* qt    = ws + OF_QT;
    float* rowv  = ws + OF_ROWV;
    int*   rowi  = (int*)(ws + OF_ROWI);
    float* colvi = ws + OF_CVI;
    int*   cmp   = (int*)(ws + OF_CMP);
    int*   cntg  = (int*)(ws + OF_CNT);
    int*   unear = (int*)(ws + OF_UNEAR);
    int*   snear = (int*)(ws + OF_SNEAR);
    float* bvg   = ws + OF_BV;
    int*   bpg   = (int*)(ws + OF_BP);
    unsigned char* amaxg = (unsigned char*)(ws + OF_AMX);

    hipMemsetAsync(d_out, 0, sizeof(float), stream);

    hipLaunchKernelGGL(knorm, dim3(1250), dim3(256), 0, stream,
                       sup, qry, unl, unl_n, sup_n, supT, qt);
    hipLaunchKernelGGL(kb, dim3(1600), dim3(256), 0, stream,
                       unl_n, supT, rowv, rowi, colvi);
    hipLaunchKernelGGL(kmerge, dim3(49), dim3(256), 0, stream,
                       rowv, rowi, colvi, unear, snear);
    hipLaunchKernelGGL(kcmp, dim3(20), dim3(256), 0, stream,
                       unear, snear, cmp, cntg);
    hipLaunchKernelGGL(kc1, dim3(1500), dim3(256), 0, stream,
                       qt, sup_n, unl_n, cmp, cntg, bvg, bpg, amaxg);
    hipLaunchKernelGGL(kce, dim3(300), dim3(64), 0, stream,
                       bvg, bpg, amaxg, qy, (float*)d_out);
}